// Round 1
// baseline (130.987 us; speedup 1.0000x reference)
//
#include <hip/hip_runtime.h>

#define HEADS 12
#define HIDDEN 1024
#define NOUT 1536
#define SEQ 512

typedef __bf16 bf16x8 __attribute__((ext_vector_type(8)));
typedef float f32x4 __attribute__((ext_vector_type(4)));

__device__ __forceinline__ void gload_lds16(const void* g, void* l) {
  __builtin_amdgcn_global_load_lds(
      (const __attribute__((address_space(1))) unsigned int*)g,
      (__attribute__((address_space(3))) unsigned int*)l, 16, 0, 0);
}

// round-to-nearest-even fp32 -> bf16 bits (inputs are finite)
__device__ __forceinline__ unsigned short f2bf(float f) {
  union { float f; unsigned u; } x;
  x.f = f;
  unsigned r = x.u + 0x7fffu + ((x.u >> 16) & 1u);
  return (unsigned short)(r >> 16);
}

// ---------- prep kernels ----------
__global__ __launch_bounds__(256) void k_convert_hidden(const float* __restrict__ in,
                                                        unsigned short* __restrict__ out) {
  int i = blockIdx.x * 256 + threadIdx.x;  // 2,097,152 threads, exact
  float4 v = ((const float4*)in)[i];
  ushort4 o;
  o.x = f2bf(v.x); o.y = f2bf(v.y); o.z = f2bf(v.z); o.w = f2bf(v.w);
  ((ushort4*)out)[i] = o;
}

__global__ __launch_bounds__(256) void k_transpose_w(const float* __restrict__ W,
                                                     unsigned short* __restrict__ Wt) {
  __shared__ unsigned short t[32][33];
  int n0 = blockIdx.x * 32;  // 48 tiles over 1536
  int k0 = blockIdx.y * 32;  // 32 tiles over 1024
  int tx = threadIdx.x & 31;
  int ty = threadIdx.x >> 5;  // 0..7
#pragma unroll
  for (int i = 0; i < 4; ++i) {
    int k = k0 + ty + i * 8;
    t[ty + i * 8][tx] = f2bf(W[(size_t)k * NOUT + n0 + tx]);
  }
  __syncthreads();
#pragma unroll
  for (int i = 0; i < 4; ++i) {
    int n = n0 + ty + i * 8;
    Wt[(size_t)n * HIDDEN + k0 + tx] = t[tx][ty + i * 8];
  }
}

__global__ __launch_bounds__(256) void k_trig(float2* __restrict__ trig) {
  int i = blockIdx.x * 256 + threadIdx.x;  // 16384 = 512 pos x 32 freq
  int pos = i >> 5, j = i & 31;
  float inv = 1.0f / powf(10000.0f, (float)(2 * j) * (1.0f / 64.0f));
  float ang = (float)pos * inv;
  trig[i] = make_float2(cosf(ang), sinf(ang));
}

// ---------- projection GEMM + bias + RoPE + q-scale ----------
__global__ __launch_bounds__(256) void k_proj(const unsigned short* __restrict__ A,   // 8192x1024 bf16
                                              const unsigned short* __restrict__ Bt,  // 1536x1024 bf16 (W^T)
                                              const float* __restrict__ bias,         // 1536
                                              const float2* __restrict__ trig,        // 512x32
                                              unsigned short* __restrict__ qb,        // [b*12+h][512][64]
                                              unsigned short* __restrict__ kb) {
  __shared__ unsigned short As[128 * 64];
  __shared__ unsigned short Bs[128 * 64];
  const int h = blockIdx.x;           // 0..11
  const int m0 = blockIdx.y * 128;    // 0..63
  const int n0 = h * 128;
  const int tid = threadIdx.x;
  const int wave = tid >> 6, lane = tid & 63;
  const int l15 = lane & 15, l4 = lane >> 4;
  const int wr = wave >> 1, wc = wave & 1;

  f32x4 acc[4][4];
#pragma unroll
  for (int a = 0; a < 4; ++a)
#pragma unroll
    for (int b2 = 0; b2 < 4; ++b2) acc[a][b2] = (f32x4){0.f, 0.f, 0.f, 0.f};

  for (int kt = 0; kt < 16; ++kt) {
    __syncthreads();
    const int kbase = kt * 64;
#pragma unroll
    for (int i = 0; i < 4; ++i) {
      int chunk = i * 256 + tid;       // 0..1023
      int r = chunk >> 3, c8 = chunk & 7;
      gload_lds16(A + (size_t)(m0 + r) * HIDDEN + kbase + c8 * 8, As + chunk * 8);
      gload_lds16(Bt + (size_t)(n0 + r) * HIDDEN + kbase + c8 * 8, Bs + chunk * 8);
    }
    asm volatile("s_waitcnt vmcnt(0)" ::: "memory");
    __syncthreads();
#pragma unroll
    for (int kk = 0; kk < 2; ++kk) {
      bf16x8 af[4], bv[4];
#pragma unroll
      for (int mi = 0; mi < 4; ++mi)
        af[mi] = *(const bf16x8*)(As + (wr * 64 + mi * 16 + l15) * 64 + kk * 32 + l4 * 8);
#pragma unroll
      for (int ni = 0; ni < 4; ++ni)
        bv[ni] = *(const bf16x8*)(Bs + (wc * 64 + ni * 16 + l15) * 64 + kk * 32 + l4 * 8);
#pragma unroll
      for (int mi = 0; mi < 4; ++mi)
#pragma unroll
        for (int ni = 0; ni < 4; ++ni)
          acc[mi][ni] = __builtin_amdgcn_mfma_f32_16x16x32_bf16(af[mi], bv[ni], acc[mi][ni], 0, 0, 0);
    }
  }

  // epilogue: bias + RoPE + scale, write q/k bf16
#pragma unroll
  for (int ni = 0; ni < 4; ++ni) {
    const int c = wc * 64 + ni * 16 + l15;  // 0..127 within head: [0,64)=q, [64,128)=k
    const int qk = c >> 6;
    const int d = c & 63;
    const int j = d >> 1;
    const int odd = d & 1;
    const float bias_v = bias[n0 + c];
    unsigned short* dst = qk ? kb : qb;
    const float scale = qk ? 1.0f : 0.125f;
#pragma unroll
    for (int mi = 0; mi < 4; ++mi) {
#pragma unroll
      for (int jj = 0; jj < 4; ++jj) {
        const int row = wr * 64 + mi * 16 + l4 * 4 + jj;
        const int m = m0 + row;
        const int bb = m >> 9, pos = m & 511;
        float v = acc[mi][ni][jj] + bias_v;
        float p = __shfl_xor(v, 1);  // partner (d^1), already biased
        float2 cs = trig[pos * 32 + j];
        float o = odd ? (v * cs.x + p * cs.y) : (v * cs.x - p * cs.y);
        o *= scale;
        dst[(((size_t)bb * HEADS + h) * SEQ + pos) * 64 + d] = f2bf(o);
      }
    }
  }
}

// ---------- batched score GEMM + mask + sigmoid ----------
__global__ __launch_bounds__(256) void k_scores(const unsigned short* __restrict__ qb,
                                                const unsigned short* __restrict__ kb,
                                                const int* __restrict__ aw,
                                                float* __restrict__ out) {
  __shared__ unsigned short Qs[128 * 64];
  __shared__ unsigned short Ks[128 * 64];
  const int bh = blockIdx.y;  // 0..191
  const int b = bh / HEADS;
  const int tq = blockIdx.x & 3, tk = blockIdx.x >> 2;
  const int q0 = tq * 128, k0 = tk * 128;
  const int tid = threadIdx.x;
  const int wave = tid >> 6, lane = tid & 63;
  const int l15 = lane & 15, l4 = lane >> 4;
  const int wr = wave >> 1, wc = wave & 1;

  const unsigned short* qsrc = qb + (size_t)bh * SEQ * 64;
  const unsigned short* ksrc = kb + (size_t)bh * SEQ * 64;

#pragma unroll
  for (int i = 0; i < 4; ++i) {
    int chunk = i * 256 + tid;
    int r = chunk >> 3, c8 = chunk & 7;
    gload_lds16(qsrc + (size_t)(q0 + r) * 64 + c8 * 8, Qs + chunk * 8);
    gload_lds16(ksrc + (size_t)(k0 + r) * 64 + c8 * 8, Ks + chunk * 8);
  }

  f32x4 acc[4][4];
#pragma unroll
  for (int a = 0; a < 4; ++a)
#pragma unroll
    for (int b2 = 0; b2 < 4; ++b2) acc[a][b2] = (f32x4){0.f, 0.f, 0.f, 0.f};

  asm volatile("s_waitcnt vmcnt(0)" ::: "memory");
  __syncthreads();

#pragma unroll
  for (int kk = 0; kk < 2; ++kk) {
    bf16x8 qf[4], kf[4];
#pragma unroll
    for (int mi = 0; mi < 4; ++mi)
      qf[mi] = *(const bf16x8*)(Qs + (wr * 64 + mi * 16 + l15) * 64 + kk * 32 + l4 * 8);
#pragma unroll
    for (int ni = 0; ni < 4; ++ni)
      kf[ni] = *(const bf16x8*)(Ks + (wc * 64 + ni * 16 + l15) * 64 + kk * 32 + l4 * 8);
#pragma unroll
    for (int mi = 0; mi < 4; ++mi)
#pragma unroll
      for (int ni = 0; ni < 4; ++ni)
        acc[mi][ni] = __builtin_amdgcn_mfma_f32_16x16x32_bf16(qf[mi], kf[ni], acc[mi][ni], 0, 0, 0);
  }

#pragma unroll
  for (int ni = 0; ni < 4; ++ni) {
    const int c = wc * 64 + ni * 16 + l15;
    const int key = k0 + c;
    const int awv = aw[b * SEQ + key];
#pragma unroll
    for (int mi = 0; mi < 4; ++mi) {
#pragma unroll
      for (int jj = 0; jj < 4; ++jj) {
        const int row = wr * 64 + mi * 16 + l4 * 4 + jj;
        const int nq = q0 + row;
        float s = acc[mi][ni][jj];
        float o = (awv == 0 || nq == key) ? 0.0f : 1.0f / (1.0f + __expf(-s));
        out[((size_t)bh * SEQ + nq) * SEQ + key] = o;
      }
    }
  }
}

extern "C" void kernel_launch(void* const* d_in, const int* in_sizes, int n_in,
                              void* d_out, int out_size, void* d_ws, size_t ws_size,
                              hipStream_t stream) {
  const float* hidden = (const float*)d_in[0];
  const int* aw = (const int*)d_in[1];
  const float* W = (const float*)d_in[2];
  const float* bias = (const float*)d_in[3];
  float* out = (float*)d_out;

  char* ws = (char*)d_ws;
  unsigned short* hidA = (unsigned short*)ws;                  // 16,777,216 B
  unsigned short* Wt = (unsigned short*)(ws + 16777216);       //  3,145,728 B
  unsigned short* qb = (unsigned short*)(ws + 19922944);       // 12,582,912 B
  unsigned short* kb = (unsigned short*)(ws + 32505856);       // 12,582,912 B
  float2* trig = (float2*)(ws + 45088768);                     //    131,072 B

  k_convert_hidden<<<8192, 256, 0, stream>>>(hidden, hidA);
  k_transpose_w<<<dim3(48, 32), 256, 0, stream>>>(W, Wt);
  k_trig<<<64, 256, 0, stream>>>(trig);
  k_proj<<<dim3(12, 64), 256, 0, stream>>>(hidA, Wt, bias, trig, qb, kb);
  k_scores<<<dim3(16, 192), 256, 0, stream>>>(qb, kb, aw, out);
}

// Round 2
// 124.679 us; speedup vs baseline: 1.0506x; 1.0506x over previous
//
#include <hip/hip_runtime.h>

#define HEADS 12
#define HIDDEN 1024
#define NOUT 1536
#define SEQ 512

typedef __bf16 bf16x8 __attribute__((ext_vector_type(8)));
typedef float f32x4 __attribute__((ext_vector_type(4)));

__device__ __forceinline__ void gload_lds16(const void* g, void* l) {
  __builtin_amdgcn_global_load_lds(
      (const __attribute__((address_space(1))) unsigned int*)g,
      (__attribute__((address_space(3))) unsigned int*)l, 16, 0, 0);
}

// round-to-nearest-even fp32 -> bf16 bits (inputs are finite)
__device__ __forceinline__ unsigned short f2bf(float f) {
  union { float f; unsigned u; } x;
  x.f = f;
  unsigned r = x.u + 0x7fffu + ((x.u >> 16) & 1u);
  return (unsigned short)(r >> 16);
}

// XCD-chunked work swizzle (nwg % 8 == 0): HW block b on XCD (b&7) takes
// work item (b&7)*per + (b>>3), so consecutive work items share one XCD's L2.
__device__ __forceinline__ int swz8(int b, int per) {
  return (b & 7) * per + (b >> 3);
}

// ---------- merged prep: convert hidden, transpose W, trig table ----------
__global__ __launch_bounds__(256) void k_prep(const float* __restrict__ hidden,
                                              unsigned short* __restrict__ hidA,
                                              const float* __restrict__ W,
                                              unsigned short* __restrict__ Wt,
                                              float2* __restrict__ trig) {
  __shared__ unsigned short t[32][33];
  const int bid = blockIdx.x;
  const int tid = threadIdx.x;
  if (bid < 8192) {
    int i = bid * 256 + tid;  // 2,097,152 float4 = 16x512x1024 exact
    float4 v = ((const float4*)hidden)[i];
    ushort4 o;
    o.x = f2bf(v.x); o.y = f2bf(v.y); o.z = f2bf(v.z); o.w = f2bf(v.w);
    ((ushort4*)hidA)[i] = o;
  } else if (bid < 8192 + 1536) {
    int tt = bid - 8192;
    int n0 = (tt % 48) * 32;
    int k0 = (tt / 48) * 32;
    int tx = tid & 31;
    int ty = tid >> 5;  // 0..7
#pragma unroll
    for (int i = 0; i < 4; ++i) {
      int k = k0 + ty + i * 8;
      t[ty + i * 8][tx] = f2bf(W[(size_t)k * NOUT + n0 + tx]);
    }
    __syncthreads();
#pragma unroll
    for (int i = 0; i < 4; ++i) {
      int n = n0 + ty + i * 8;
      Wt[(size_t)n * HIDDEN + k0 + tx] = t[tx][ty + i * 8];
    }
  } else {
    int i = (bid - 9728) * 256 + tid;  // 16384 = 512 pos x 32 freq
    int pos = i >> 5, j = i & 31;
    float inv = 1.0f / powf(10000.0f, (float)(2 * j) * (1.0f / 64.0f));
    float ang = (float)pos * inv;
    trig[i] = make_float2(cosf(ang), sinf(ang));
  }
}

// ---------- projection GEMM + bias + RoPE + q-scale ----------
__global__ __launch_bounds__(256) void k_proj(const unsigned short* __restrict__ A,   // 8192x1024 bf16
                                              const unsigned short* __restrict__ Bt,  // 1536x1024 bf16 (W^T)
                                              const float* __restrict__ bias,         // 1536
                                              const float2* __restrict__ trig,        // 512x32
                                              unsigned short* __restrict__ qb,        // [b*12+h][512][64]
                                              unsigned short* __restrict__ kb) {
  __shared__ unsigned short As[128 * 64];
  __shared__ unsigned short Bs[128 * 64];
  const int lin = swz8(blockIdx.x, 96);  // 768 work items, 96 per XCD
  const int h = lin % 12;                // head fastest: 12 heads of one m-tile co-reside
  const int m0 = (lin / 12) * 128;
  const int n0 = h * 128;
  const int tid = threadIdx.x;
  const int wave = tid >> 6, lane = tid & 63;
  const int l15 = lane & 15, l4 = lane >> 4;
  const int wr = wave >> 1, wc = wave & 1;

  f32x4 acc[4][4];
#pragma unroll
  for (int a = 0; a < 4; ++a)
#pragma unroll
    for (int b2 = 0; b2 < 4; ++b2) acc[a][b2] = (f32x4){0.f, 0.f, 0.f, 0.f};

  for (int kt = 0; kt < 16; ++kt) {
    __syncthreads();
    const int kbase = kt * 64;
#pragma unroll
    for (int i = 0; i < 4; ++i) {
      int chunk = i * 256 + tid;       // 0..1023
      int r = chunk >> 3, c8 = chunk & 7;
      gload_lds16(A + (size_t)(m0 + r) * HIDDEN + kbase + c8 * 8, As + chunk * 8);
      gload_lds16(Bt + (size_t)(n0 + r) * HIDDEN + kbase + c8 * 8, Bs + chunk * 8);
    }
    asm volatile("s_waitcnt vmcnt(0)" ::: "memory");
    __syncthreads();
#pragma unroll
    for (int kk = 0; kk < 2; ++kk) {
      bf16x8 af[4], bv[4];
#pragma unroll
      for (int mi = 0; mi < 4; ++mi)
        af[mi] = *(const bf16x8*)(As + (wr * 64 + mi * 16 + l15) * 64 + kk * 32 + l4 * 8);
#pragma unroll
      for (int ni = 0; ni < 4; ++ni)
        bv[ni] = *(const bf16x8*)(Bs + (wc * 64 + ni * 16 + l15) * 64 + kk * 32 + l4 * 8);
#pragma unroll
      for (int mi = 0; mi < 4; ++mi)
#pragma unroll
        for (int ni = 0; ni < 4; ++ni)
          acc[mi][ni] = __builtin_amdgcn_mfma_f32_16x16x32_bf16(af[mi], bv[ni], acc[mi][ni], 0, 0, 0);
    }
  }

  // epilogue: bias + RoPE + scale, write q/k bf16
#pragma unroll
  for (int ni = 0; ni < 4; ++ni) {
    const int c = wc * 64 + ni * 16 + l15;  // 0..127 within head: [0,64)=q, [64,128)=k
    const int qk = c >> 6;
    const int d = c & 63;
    const int j = d >> 1;
    const int odd = d & 1;
    const float bias_v = bias[n0 + c];
    unsigned short* dst = qk ? kb : qb;
    const float scale = qk ? 1.0f : 0.125f;
#pragma unroll
    for (int mi = 0; mi < 4; ++mi) {
#pragma unroll
      for (int jj = 0; jj < 4; ++jj) {
        const int row = wr * 64 + mi * 16 + l4 * 4 + jj;
        const int m = m0 + row;
        const int bb = m >> 9, pos = m & 511;
        float v = acc[mi][ni][jj] + bias_v;
        float p = __shfl_xor(v, 1);  // partner (d^1), already biased
        float2 cs = trig[pos * 32 + j];
        float o = odd ? (v * cs.x + p * cs.y) : (v * cs.x - p * cs.y);
        o *= scale;
        dst[(((size_t)bb * HEADS + h) * SEQ + pos) * 64 + d] = f2bf(o);
      }
    }
  }
}

// ---------- batched score GEMM + mask + sigmoid ----------
// One block = one (bh, q-tile); K loops over 4 tiles. Q staged once.
__global__ __launch_bounds__(256) void k_scores(const unsigned short* __restrict__ qb,
                                                const unsigned short* __restrict__ kb,
                                                const int* __restrict__ aw,
                                                float* __restrict__ out) {
  __shared__ unsigned short Qs[128 * 64];
  __shared__ unsigned short Ks[128 * 64];
  const int lin = swz8(blockIdx.x, 96);  // 768 = 192 bh x 4 q-tiles
  const int bh = lin >> 2;
  const int b = bh / HEADS;
  const int q0 = (lin & 3) * 128;
  const int tid = threadIdx.x;
  const int wave = tid >> 6, lane = tid & 63;
  const int l15 = lane & 15, l4 = lane >> 4;
  const int wr = wave >> 1, wc = wave & 1;

  const unsigned short* qsrc = qb + (size_t)bh * SEQ * 64 + (size_t)q0 * 64;
  const unsigned short* ksrc = kb + (size_t)bh * SEQ * 64;

#pragma unroll
  for (int i = 0; i < 4; ++i) {
    int chunk = i * 256 + tid;
    int r = chunk >> 3, c8 = chunk & 7;
    gload_lds16(qsrc + (size_t)r * 64 + c8 * 8, Qs + chunk * 8);
    gload_lds16(ksrc + (size_t)r * 64 + c8 * 8, Ks + chunk * 8);
  }
  asm volatile("s_waitcnt vmcnt(0)" ::: "memory");
  __syncthreads();

  for (int tk = 0; tk < 4; ++tk) {
    const int k0 = tk * 128;
    f32x4 acc[4][4];
#pragma unroll
    for (int a = 0; a < 4; ++a)
#pragma unroll
      for (int b2 = 0; b2 < 4; ++b2) acc[a][b2] = (f32x4){0.f, 0.f, 0.f, 0.f};

#pragma unroll
    for (int kk = 0; kk < 2; ++kk) {
      bf16x8 qf[4], kf[4];
#pragma unroll
      for (int mi = 0; mi < 4; ++mi)
        qf[mi] = *(const bf16x8*)(Qs + (wr * 64 + mi * 16 + l15) * 64 + kk * 32 + l4 * 8);
#pragma unroll
      for (int ni = 0; ni < 4; ++ni)
        kf[ni] = *(const bf16x8*)(Ks + (wc * 64 + ni * 16 + l15) * 64 + kk * 32 + l4 * 8);
#pragma unroll
      for (int mi = 0; mi < 4; ++mi)
#pragma unroll
        for (int ni = 0; ni < 4; ++ni)
          acc[mi][ni] = __builtin_amdgcn_mfma_f32_16x16x32_bf16(qf[mi], kf[ni], acc[mi][ni], 0, 0, 0);
    }

    // epilogue for this k-range (global stores overlap next staging latency)
#pragma unroll
    for (int ni = 0; ni < 4; ++ni) {
      const int c = wc * 64 + ni * 16 + l15;
      const int key = k0 + c;
      const int awv = aw[b * SEQ + key];
#pragma unroll
      for (int mi = 0; mi < 4; ++mi) {
#pragma unroll
        for (int jj = 0; jj < 4; ++jj) {
          const int row = wr * 64 + mi * 16 + l4 * 4 + jj;
          const int nq = q0 + row;
          float s = acc[mi][ni][jj];
          float o = (awv == 0 || nq == key) ? 0.0f : 1.0f / (1.0f + __expf(-s));
          out[((size_t)bh * SEQ + nq) * SEQ + key] = o;
        }
      }
    }

    if (tk < 3) {
      __syncthreads();  // all MFMA reads of Ks done
#pragma unroll
      for (int i = 0; i < 4; ++i) {
        int chunk = i * 256 + tid;
        int r = chunk >> 3, c8 = chunk & 7;
        gload_lds16(ksrc + (size_t)(k0 + 128 + r) * 64 + c8 * 8, Ks + chunk * 8);
      }
      asm volatile("s_waitcnt vmcnt(0)" ::: "memory");
      __syncthreads();
    }
  }
}

extern "C" void kernel_launch(void* const* d_in, const int* in_sizes, int n_in,
                              void* d_out, int out_size, void* d_ws, size_t ws_size,
                              hipStream_t stream) {
  const float* hidden = (const float*)d_in[0];
  const int* aw = (const int*)d_in[1];
  const float* W = (const float*)d_in[2];
  const float* bias = (const float*)d_in[3];
  float* out = (float*)d_out;

  char* ws = (char*)d_ws;
  unsigned short* hidA = (unsigned short*)ws;                  // 16,777,216 B
  unsigned short* Wt = (unsigned short*)(ws + 16777216);       //  3,145,728 B
  unsigned short* qb = (unsigned short*)(ws + 19922944);       // 12,582,912 B
  unsigned short* kb = (unsigned short*)(ws + 32505856);       // 12,582,912 B
  float2* trig = (float2*)(ws + 45088768);                     //    131,072 B

  k_prep<<<9792, 256, 0, stream>>>(hidden, hidA, W, Wt, trig);
  k_proj<<<768, 256, 0, stream>>>(hidA, Wt, bias, trig, qb, kb);
  k_scores<<<768, 256, 0, stream>>>(qb, kb, aw, out);
}